// Round 5
// baseline (165.699 us; speedup 1.0000x reference)
//
#include <hip/hip_runtime.h>
#include <math.h>

#define N_NODES 2048
#define IN_F 128
#define OUT_F 32
#define NEG_INF -9e15f

// Swizzled word index for p_s: one float4 per k holding p[k][i0..i0+3].
// word = 4k ^ (S<<2), S = ((k>>3)^(k>>5))&7.
//  - phase-2 writes (k=4t+kk, fixed kk per inst): 8-lane groups cover all 8
//    bank quads.
//  - phase-3 reads (k=32c+it, fixed it per inst, c varies per 8-lane group):
//    8 c-groups hit 8 distinct quads, broadcast within each group.
// Hand-verified conflict-free for both patterns; bijective (triangular XOR).
__device__ __forceinline__ int pwd(int k) {
    return (k << 2) ^ ((((k >> 3) ^ (k >> 5)) & 7) << 2);
}

// ---------------------------------------------------------------------------
// Kernel A: Wh1[N][32] = h @ W[:128], Wh2T[32][N] = (h @ W[128:])^T,
//           Q[k] = 0.6*sum_f a[f]*Wh2[k,f], C[f] = 0.4*a[f].
// (leakyrelu(x) = 0.6x + 0.4|x|; per-row-i constant cancels in softmax.)
// ---------------------------------------------------------------------------
__global__ __launch_bounds__(256) void precompute_wh(
    const float* __restrict__ h, const float* __restrict__ W,
    const float* __restrict__ a,
    float* __restrict__ Wh1, float* __restrict__ Wh2T,
    float* __restrict__ Q, float* __restrict__ C)
{
    __shared__ float h_s[8][IN_F];
    __shared__ float tr[8][OUT_F];
    const int t = threadIdx.x;
    const int i0 = blockIdx.x * 8;

    ((float4*)&h_s[0][0])[t] = ((const float4*)(h + (size_t)i0 * IN_F))[t];
    __syncthreads();

    const int f = t & 31;
    const int r = t >> 5;
    float acc1 = 0.f, acc2 = 0.f;
    #pragma unroll 8
    for (int c = 0; c < IN_F; ++c) {
        const float hv = h_s[r][c];
        acc1 = fmaf(hv, W[c * OUT_F + f], acc1);
        acc2 = fmaf(hv, W[(IN_F + c) * OUT_F + f], acc2);
    }
    Wh1[(i0 + r) * OUT_F + f] = acc1;
    tr[r][f] = acc2;

    float q = 0.6f * a[f] * acc2;
    #pragma unroll
    for (int off = 16; off > 0; off >>= 1) q += __shfl_xor(q, off, 64);
    if (f == 0) Q[i0 + r] = q;
    if (blockIdx.x == 0 && t < OUT_F) C[t] = 0.4f * a[t];

    __syncthreads();
    const int f2 = t >> 3, r2 = t & 7;
    Wh2T[f2 * N_NODES + i0 + r2] = tr[r2][f2];
}

// ---------------------------------------------------------------------------
// Kernel B: TI=4 rows/block, 512 threads, grid 512 (2 blocks/CU, 16 waves/CU).
// Thread owns k-quad 4t. All global loads are float4/int4 (1 KB/wave-inst)
// and explicitly double-buffered: group g+1's loads issue before group g's
// compute (~256 VALU-cycles of latency cover), adj/Q issue under group 6-7.
// ---------------------------------------------------------------------------
__global__ __launch_bounds__(512, 4) void gat_row(
    const float* __restrict__ Wh1, const float* __restrict__ Wh2T,
    const float* __restrict__ Q, const float* __restrict__ C,
    const int* __restrict__ adj, float* __restrict__ out)
{
    __shared__ __align__(16) float p_s[4 * N_NODES];     // 32 KB, swizzled
    __shared__ __align__(16) float w1s[4][OUT_F];        // 512 B
    __shared__ __align__(16) float part[8][4][OUT_F];    // 4 KB
    __shared__ float redM[4][8], redL[4][8], Mfin[4];

    const int t = threadIdx.x;
    const int i0 = blockIdx.x * 4;
    const int k0 = 4 * t;
    const int lane = t & 63, wid = t >> 6;

    if (t < 4 * OUT_F) w1s[t >> 5][t & 31] = Wh1[i0 * OUT_F + t];
    __syncthreads();

    // ---------------- Phase 1: scores (pipelined) ----------------
    float acc[4][4];
    #pragma unroll
    for (int i = 0; i < 4; ++i)
        #pragma unroll
        for (int c = 0; c < 4; ++c) acc[i][c] = 0.f;

    float4 buf[2][4];
    #pragma unroll
    for (int e = 0; e < 4; ++e)
        buf[0][e] = *(const float4*)(Wh2T + (size_t)e * N_NODES + k0);

    int4 ad[4];
    float4 q4;
    #pragma unroll
    for (int g = 0; g < 8; ++g) {
        if (g < 7) {
            #pragma unroll
            for (int e = 0; e < 4; ++e)
                buf[(g + 1) & 1][e] =
                    *(const float4*)(Wh2T + (size_t)((g + 1) * 4 + e) * N_NODES + k0);
        }
        if (g == 6) {   // adj + Q latency hides under groups 6-7 compute
            #pragma unroll
            for (int i = 0; i < 4; ++i)
                ad[i] = *(const int4*)(adj + (size_t)(i0 + i) * N_NODES + k0);
            q4 = *(const float4*)(Q + k0);
        }
        #pragma unroll
        for (int i = 0; i < 4; ++i) {
            const float4 w1 = *(const float4*)&w1s[i][4 * g];   // LDS broadcast
            #pragma unroll
            for (int e = 0; e < 4; ++e) {
                const float cf = C[4 * g + e];                  // uniform -> sgpr
                const float4 w2 = buf[g & 1][e];
                const float w1c = (e == 0) ? w1.x : (e == 1) ? w1.y
                                 : (e == 2) ? w1.z : w1.w;
                acc[i][0] = fmaf(cf, fabsf(w1c + w2.x), acc[i][0]);
                acc[i][1] = fmaf(cf, fabsf(w1c + w2.y), acc[i][1]);
                acc[i][2] = fmaf(cf, fabsf(w1c + w2.z), acc[i][2]);
                acc[i][3] = fmaf(cf, fabsf(w1c + w2.w), acc[i][3]);
            }
        }
    }

    // mask + Q, per-i block max
    #pragma unroll
    for (int i = 0; i < 4; ++i) {
        acc[i][0] = (ad[i].x > 0) ? acc[i][0] + q4.x : NEG_INF;
        acc[i][1] = (ad[i].y > 0) ? acc[i][1] + q4.y : NEG_INF;
        acc[i][2] = (ad[i].z > 0) ? acc[i][2] + q4.z : NEG_INF;
        acc[i][3] = (ad[i].w > 0) ? acc[i][3] + q4.w : NEG_INF;
        float mm = fmaxf(fmaxf(acc[i][0], acc[i][1]), fmaxf(acc[i][2], acc[i][3]));
        #pragma unroll
        for (int off = 32; off > 0; off >>= 1)
            mm = fmaxf(mm, __shfl_xor(mm, off, 64));
        if (lane == 0) redM[i][wid] = mm;
    }
    __syncthreads();
    if (t < 32) {           // i = t>>3, w = t&7 (all in wave 0)
        float v = redM[t >> 3][t & 7];
        #pragma unroll
        for (int off = 4; off > 0; off >>= 1)
            v = fmaxf(v, __shfl_xor(v, off, 64));
        if ((t & 7) == 0) Mfin[t >> 3] = v;
    }
    __syncthreads();

    // ---------------- Phase 2: exp + L-reduce + p store ----------------
    float pr[4][4];
    #pragma unroll
    for (int i = 0; i < 4; ++i) {
        const float M = Mfin[i];
        float ll = 0.f;
        #pragma unroll
        for (int c = 0; c < 4; ++c) {
            pr[i][c] = __expf(acc[i][c] - M);
            ll += pr[i][c];
        }
        #pragma unroll
        for (int off = 32; off > 0; off >>= 1)
            ll += __shfl_xor(ll, off, 64);
        if (lane == 0) redL[i][wid] = ll;
    }
    #pragma unroll
    for (int kk = 0; kk < 4; ++kk)
        *(float4*)&p_s[pwd(k0 + kk)] =
            make_float4(pr[0][kk], pr[1][kk], pr[2][kk], pr[3][kk]);
    __syncthreads();

    // ---------------- Phase 3: h' = (p @ Wh1)/L (pipelined) ----------------
    const int fq = (t & 7) * 4;     // f quad
    const int c  = t >> 3;          // 64 chunks of 32 k
    float4 av[4];
    #pragma unroll
    for (int i = 0; i < 4; ++i) av[i] = make_float4(0.f, 0.f, 0.f, 0.f);

    float4 wbuf[2][4];
    #pragma unroll
    for (int e = 0; e < 4; ++e)
        wbuf[0][e] = *(const float4*)(Wh1 + (size_t)(32 * c + e) * OUT_F + fq);

    #pragma unroll
    for (int kg = 0; kg < 8; ++kg) {
        if (kg < 7) {
            #pragma unroll
            for (int e = 0; e < 4; ++e)
                wbuf[(kg + 1) & 1][e] =
                    *(const float4*)(Wh1 + (size_t)(32 * c + 4 * (kg + 1) + e) * OUT_F + fq);
        }
        #pragma unroll
        for (int e = 0; e < 4; ++e) {
            const int k = 32 * c + 4 * kg + e;
            const float4 p = *(const float4*)&p_s[pwd(k)];   // broadcast b128
            const float4 w = wbuf[kg & 1][e];
            av[0].x = fmaf(p.x, w.x, av[0].x); av[0].y = fmaf(p.x, w.y, av[0].y);
            av[0].z = fmaf(p.x, w.z, av[0].z); av[0].w = fmaf(p.x, w.w, av[0].w);
            av[1].x = fmaf(p.y, w.x, av[1].x); av[1].y = fmaf(p.y, w.y, av[1].y);
            av[1].z = fmaf(p.y, w.z, av[1].z); av[1].w = fmaf(p.y, w.w, av[1].w);
            av[2].x = fmaf(p.z, w.x, av[2].x); av[2].y = fmaf(p.z, w.y, av[2].y);
            av[2].z = fmaf(p.z, w.z, av[2].z); av[2].w = fmaf(p.z, w.w, av[2].w);
            av[3].x = fmaf(p.w, w.x, av[3].x); av[3].y = fmaf(p.w, w.y, av[3].y);
            av[3].z = fmaf(p.w, w.z, av[3].z); av[3].w = fmaf(p.w, w.w, av[3].w);
        }
    }

    // fold the 8 c-groups of each wave (c-low bits are lane bits 3-5)
    #pragma unroll
    for (int off = 8; off <= 32; off <<= 1) {
        #pragma unroll
        for (int i = 0; i < 4; ++i) {
            av[i].x += __shfl_xor(av[i].x, off, 64);
            av[i].y += __shfl_xor(av[i].y, off, 64);
            av[i].z += __shfl_xor(av[i].z, off, 64);
            av[i].w += __shfl_xor(av[i].w, off, 64);
        }
    }
    if (lane < 8) {                 // lane b holds fq = 4b sums
        #pragma unroll
        for (int i = 0; i < 4; ++i)
            *(float4*)&part[wid][i][4 * lane] = av[i];
    }
    __syncthreads();

    // final cross-wave reduce + 1/L + ELU + store
    if (t < 4 * OUT_F) {
        const int i = t >> 5, f = t & 31;
        float s = 0.f;
        #pragma unroll
        for (int w = 0; w < 8; ++w) s += part[w][i][f];
        float L = 0.f;
        #pragma unroll
        for (int w = 0; w < 8; ++w) L += redL[i][w];
        const float val = s / L;
        out[(i0 + i) * OUT_F + f] = (val > 0.f) ? val : (__expf(val) - 1.f);
    }
}

extern "C" void kernel_launch(void* const* d_in, const int* in_sizes, int n_in,
                              void* d_out, int out_size, void* d_ws, size_t ws_size,
                              hipStream_t stream) {
    const float* h   = (const float*)d_in[0];
    const int*   adj = (const int*)d_in[1];
    const float* W   = (const float*)d_in[2];
    const float* a   = (const float*)d_in[3];
    float* out = (float*)d_out;

    float* Wh1  = (float*)d_ws;                  // 2048*32
    float* Wh2T = Wh1 + N_NODES * OUT_F;         // 32*2048
    float* Q    = Wh2T + N_NODES * OUT_F;        // 2048
    float* C    = Q + N_NODES;                   // 32

    precompute_wh<<<N_NODES / 8, 256, 0, stream>>>(h, W, a, Wh1, Wh2T, Q, C);
    gat_row<<<N_NODES / 4, 512, 0, stream>>>(Wh1, Wh2T, Q, C, adj, out);
}